// Round 8
// baseline (1387.623 us; speedup 1.0000x reference)
//
#include <hip/hip_runtime.h>
#include <hip/hip_bf16.h>
#include <stdint.h>

#define BB 64
#define DD 2048
#define VV 50257
#define NB 4096      // histogram bins
#define MAXC 2048    // boundary-bin collect capacity

struct U2 { unsigned x, y; };

__device__ __forceinline__ unsigned rotl32(unsigned v, int r) {
  return (v << r) | (v >> (32 - r));
}

// JAX threefry2x32 (jax/_src/prng.py lowering), 20 rounds.
__device__ __forceinline__ U2 threefry2x32(unsigned k0, unsigned k1,
                                           unsigned x0, unsigned x1) {
  unsigned k2 = k0 ^ k1 ^ 0x1BD11BDAu;
  x0 += k0; x1 += k1;
#define TF_R4(r1, r2, r3, r4)                         \
  x0 += x1; x1 = rotl32(x1, r1); x1 ^= x0;            \
  x0 += x1; x1 = rotl32(x1, r2); x1 ^= x0;            \
  x0 += x1; x1 = rotl32(x1, r3); x1 ^= x0;            \
  x0 += x1; x1 = rotl32(x1, r4); x1 ^= x0;
  TF_R4(13, 15, 26, 6)   x0 += k1; x1 += k2 + 1u;
  TF_R4(17, 29, 16, 24)  x0 += k2; x1 += k0 + 2u;
  TF_R4(13, 15, 26, 6)   x0 += k0; x1 += k1 + 3u;
  TF_R4(17, 29, 16, 24)  x0 += k1; x1 += k2 + 4u;
  TF_R4(13, 15, 26, 6)   x0 += k2; x1 += k0 + 5u;
#undef TF_R4
  U2 r; r.x = x0; r.y = x1; return r;
}

// VALIDATED (R5): partitionable threefry bits = XOR-fold of both cipher words,
// counter (hi=0, lo=e), key (0, 42).
__device__ __forceinline__ unsigned jax_random_bits(unsigned e) {
  U2 r = threefry2x32(0u, 42u, 0u, e);
  return r.x ^ r.y;
}

__device__ __forceinline__ unsigned mono_key(float zi) {
  unsigned bb = __float_as_uint(zi);
  return bb ^ ((bb >> 31) ? 0xFFFFFFFFu : 0x80000000u);
}

// xT[d][b] = x[b][d] so GEMM inner loop reads wave-uniform x (scalar loads).
__global__ __launch_bounds__(256) void transpose_kernel(
    const float* __restrict__ x, float* __restrict__ xT) {
  int i = blockIdx.x * 256 + threadIdx.x;
  if (i < BB * DD) {
    int b = i >> 11;
    int d = i & 2047;
    xT[d * BB + b] = x[i];
  }
}

// Split-K GEMM, 512-thread blocks, two row-groups:
//   tid<256  -> col bx*256+tid, rows  0..31
//   tid>=256 -> same cols,      rows 32..63
// acc[32] (vs R7 acc[64]) halves per-thread registers -> 2x waves/CU for
// latency hiding (R7: 25.7% occ, VALUBusy 34%, 1.16 TB/s = latency-bound).
// Both halves stream the same W stripe with tiny reuse distance -> L1/L2
// hits, so HBM W traffic stays ~1x. Simple loop: R7's hand-pipeline hurt
// (compiler schedules better; documented Common-mistake #5).
__global__ __launch_bounds__(512, 4) void gemm_splitk_kernel(
    const float* __restrict__ xT, const float* __restrict__ W,
    float* __restrict__ partial, int kc) {
  const int tcol = threadIdx.x & 255;
  const int half = threadIdx.x >> 8;          // wave-uniform (64-lane waves)
  const int v = blockIdx.x * 256 + tcol;
  const int vc = (v < VV) ? v : (VV - 1);
  const int d0 = blockIdx.y * kc;
  const int b0 = half * 32;
  float acc[32];
#pragma unroll
  for (int b = 0; b < 32; ++b) acc[b] = 0.0f;
  const float* wp = W + (size_t)d0 * VV + vc;
  const float* xr = xT + d0 * BB + b0;
#pragma unroll 4
  for (int d = 0; d < kc; ++d) {
    const float w = wp[(size_t)d * VV];
    const float* xv = xr + d * BB;            // wave-uniform -> scalar loads
#pragma unroll
    for (int b = 0; b < 32; ++b) acc[b] = fmaf(xv[b], w, acc[b]);
  }
  if (v < VV) {
    float* pp = partial + (size_t)blockIdx.y * BB * VV + (size_t)b0 * VV + v;
#pragma unroll
    for (int b = 0; b < 32; ++b) pp[(size_t)b * VV] = acc[b];
  }
}

// float4 flat reduce: partial planes are [s][flat], flat-contiguous.
__global__ __launch_bounds__(256) void reduce_bias_kernel(
    const float* __restrict__ partial, const float* __restrict__ bias,
    float* __restrict__ logits, int sk) {
  const size_t tot4 = (size_t)BB * VV / 4;   // 3216448 / 4 = 804112
  size_t i = (size_t)blockIdx.x * 256 + threadIdx.x;
  if (i >= tot4) return;
  float4 acc;
  {
    size_t f = i * 4;
    int v0 = (int)(f % VV);
    acc.x = bias[v0];
    acc.y = bias[(v0 + 1 == VV) ? 0 : v0 + 1];
    acc.z = bias[(v0 + 1 >= VV) ? (v0 + 2 - VV) : v0 + 2];
    acc.w = bias[(v0 + 2 >= VV) ? (v0 + 3 - VV) : v0 + 3];
  }
  for (int s = 0; s < sk; ++s) {
    float4 p = ((const float4*)(partial + (size_t)s * BB * VV))[i];
    acc.x += p.x; acc.y += p.y; acc.z += p.z; acc.w += p.w;
  }
  ((float4*)logits)[i] = acc;
}

// Legacy fused GEMM (validated R5) — fallback if ws too small for split-K.
__global__ __launch_bounds__(256, 1) void gemm_kernel(
    const float* __restrict__ xT, const float* __restrict__ W,
    const float* __restrict__ bias, float* __restrict__ logits) {
  const int v = blockIdx.x * 256 + threadIdx.x;
  const int vc = (v < VV) ? v : (VV - 1);
  float acc[BB];
#pragma unroll
  for (int b = 0; b < BB; ++b) acc[b] = 0.0f;
  const float* wp = W + vc;
#pragma unroll 2
  for (int d = 0; d < DD; ++d) {
    const float w = wp[(size_t)d * VV];
    const float* xr = xT + d * BB;
#pragma unroll
    for (int b = 0; b < BB; ++b) acc[b] = fmaf(xr[b], w, acc[b]);
  }
  if (v < VV) {
    const float bv = bias[v];
#pragma unroll
    for (int b = 0; b < BB; ++b) logits[(size_t)b * VV + v] = acc[b] + bv;
  }
}

// Per row: max -> histogram of w=expf(z-m) binned by (m-z)*256 -> scan to find
// boundary bin (S_above <= C < S_above+bin) -> exact prefix sums within bin
// ((key desc, idx asc) order, same semantics as R5's validated binary search)
// -> t* = min kept key -> gumbel argmax over key >= t*. 4 logits passes vs 35.
__global__ __launch_bounds__(1024) void nucleus_sample_kernel(
    const float* __restrict__ logits, int* __restrict__ out) {
  __shared__ double sd[1024];
  __shared__ float sf[1024];
  __shared__ unsigned su[1024];
  __shared__ int si[1024];
  __shared__ double bins[NB];
  __shared__ int cidx[MAXC];
  __shared__ unsigned ckey[MAXC];
  __shared__ double cw[MAXC];
  __shared__ int ccount;
  __shared__ int sh_chunk;
  __shared__ int sh_bstar;
  __shared__ double sh_sabove;

  const int row = blockIdx.x;
  const int tid = threadIdx.x;
  const float* z = logits + (size_t)row * VV;

  for (int i = tid; i < NB; i += 1024) bins[i] = 0.0;
  if (tid == 0) { ccount = 0; sh_chunk = -1; sh_bstar = -1; }
  __syncthreads();

  // pass 1: row max
  float mx = -3.4e38f;
  for (int i = tid; i < VV; i += 1024) mx = fmaxf(mx, z[i]);
  sf[tid] = mx; __syncthreads();
  for (int s = 512; s > 0; s >>= 1) {
    if (tid < s) sf[tid] = fmaxf(sf[tid], sf[tid + s]);
    __syncthreads();
  }
  const float m = sf[0];
  __syncthreads();

  // pass 2: histogram
  for (int i = tid; i < VV; i += 1024) {
    float zi = z[i];
    int bin = (int)((m - zi) * 256.0f);
    bin = (bin < 0) ? 0 : ((bin > NB - 1) ? NB - 1 : bin);
    atomicAdd(&bins[bin], (double)expf(zi - m));
  }
  __syncthreads();

  // inclusive scan over 1024 chunk-sums (4 bins/chunk), f64
  {
    double c = bins[4 * tid] + bins[4 * tid + 1] + bins[4 * tid + 2] + bins[4 * tid + 3];
    sd[tid] = c; __syncthreads();
    for (int off = 1; off < 1024; off <<= 1) {
      double vv = (tid >= off) ? sd[tid - off] : 0.0;
      __syncthreads();
      sd[tid] += vv;
      __syncthreads();
    }
  }
  const double Z = sd[1023];
  const double C = (double)0.9f * Z;

  if (sd[tid] > C && (tid == 0 || sd[tid - 1] <= C)) sh_chunk = tid;
  __syncthreads();
  if (tid == 0) {
    int tc = sh_chunk;
    if (tc >= 0) {
      double run = (tc > 0) ? sd[tc - 1] : 0.0;
      for (int k = 0; k < 4; ++k) {
        double bw = bins[4 * tc + k];
        if (run + bw > C) { sh_bstar = 4 * tc + k; sh_sabove = run; break; }
        run += bw;
      }
    }
  }
  __syncthreads();
  const int bstar = sh_bstar;
  unsigned tkey = 0u;

  if (bstar >= 0) {
    const double Sab = sh_sabove;
    // pass 3: collect boundary-bin elements
    for (int i = tid; i < VV; i += 1024) {
      float zi = z[i];
      int bin = (int)((m - zi) * 256.0f);
      bin = (bin < 0) ? 0 : ((bin > NB - 1) ? NB - 1 : bin);
      if (bin == bstar) {
        int slot = atomicAdd(&ccount, 1);
        if (slot < MAXC) {
          ckey[slot] = mono_key(zi);
          cidx[slot] = i;
          cw[slot] = (double)expf(zi - m);
        }
      }
    }
    __syncthreads();
    int n = ccount; if (n > MAXC) n = MAXC;
    // kept iff exclusive prefix (in (key desc, idx asc) order) <= C
    unsigned mk = 0xFFFFFFFFu;
    for (int i = tid; i < n; i += 1024) {
      unsigned ki = ckey[i]; int ii = cidx[i];
      double T = Sab;
      for (int j = 0; j < n; ++j) {
        unsigned kj = ckey[j];
        if (kj > ki || (kj == ki && cidx[j] < ii)) T += cw[j];
      }
      if (T <= C) mk = (ki < mk) ? ki : mk;
    }
    su[tid] = mk; __syncthreads();
    for (int s = 512; s > 0; s >>= 1) {
      if (tid < s) su[tid] = min(su[tid], su[tid + s]);
      __syncthreads();
    }
    tkey = su[0];
    __syncthreads();
  }
  const unsigned tstar = tkey;

  // pass 4: gumbel argmax over kept tokens (validated R5 code path)
  float best = -3.4e38f; int bidx = 0x7FFFFFFF;
  for (int i = tid; i < VV; i += 1024) {
    float zi = z[i];
    if (mono_key(zi) < tstar) continue;
    unsigned e = (unsigned)row * (unsigned)VV + (unsigned)i;
    unsigned bits = jax_random_bits(e);
    float f = __uint_as_float((bits >> 9) | 0x3F800000u) - 1.0f;
    float u = fmaxf(1.17549435082228750797e-38f, f);
    float g = -logf(-logf(u));
    float sc = zi + g;
    if (sc > best) { best = sc; bidx = i; }
  }
  sf[tid] = best; si[tid] = bidx; __syncthreads();
  for (int s = 512; s > 0; s >>= 1) {
    if (tid < s) {
      float ob = sf[tid + s]; int oi = si[tid + s];
      if (ob > sf[tid] || (ob == sf[tid] && oi < si[tid])) {
        sf[tid] = ob; si[tid] = oi;
      }
    }
    __syncthreads();
  }
  if (tid == 0) out[row] = si[0];
}

extern "C" void kernel_launch(void* const* d_in, const int* in_sizes, int n_in,
                              void* d_out, int out_size, void* d_ws, size_t ws_size,
                              hipStream_t stream) {
  const float* x = (const float*)d_in[0];
  const float* W = (const float*)d_in[1];
  const float* bias = (const float*)d_in[2];
  int* out = (int*)d_out;
  char* ws = (char*)d_ws;

  const size_t offXT = 0;                       // 524288 B
  const size_t offLog = 524288;                 // 12865792 B
  const size_t offPart = offLog + 12865792;     // sk * 12865792 B
  float* xT = (float*)(ws + offXT);
  float* logits = (float*)(ws + offLog);
  float* partial = (float*)(ws + offPart);

  int sk = 0;
  for (int c = 8; c >= 2; c >>= 1) {
    if (offPart + (size_t)c * 12865792 <= ws_size) { sk = c; break; }
  }

  transpose_kernel<<<(BB * DD + 255) / 256, 256, 0, stream>>>(x, xT);
  const int vblocks = (VV + 255) / 256;
  if (sk) {
    dim3 g(vblocks, sk);
    gemm_splitk_kernel<<<g, 512, 0, stream>>>(xT, W, partial, DD / sk);
    const size_t tot4 = (size_t)BB * VV / 4;
    reduce_bias_kernel<<<(unsigned)((tot4 + 255) / 256), 256, 0, stream>>>(
        partial, bias, logits, sk);
  } else {
    gemm_kernel<<<vblocks, 256, 0, stream>>>(xT, W, bias, logits);
  }
  nucleus_sample_kernel<<<BB, 1024, 0, stream>>>(logits, out);
}

// Round 9
// 428.537 us; speedup vs baseline: 3.2380x; 3.2380x over previous
//
#include <hip/hip_runtime.h>
#include <hip/hip_bf16.h>
#include <stdint.h>

#define BB 64
#define DD 2048
#define VV 50257
#define NB 4096      // histogram bins
#define MAXC 2048    // boundary-bin collect capacity
#define CH 64        // K-chunk staged in LDS

struct U2 { unsigned x, y; };

__device__ __forceinline__ unsigned rotl32(unsigned v, int r) {
  return (v << r) | (v >> (32 - r));
}

// JAX threefry2x32 (jax/_src/prng.py lowering), 20 rounds.
__device__ __forceinline__ U2 threefry2x32(unsigned k0, unsigned k1,
                                           unsigned x0, unsigned x1) {
  unsigned k2 = k0 ^ k1 ^ 0x1BD11BDAu;
  x0 += k0; x1 += k1;
#define TF_R4(r1, r2, r3, r4)                         \
  x0 += x1; x1 = rotl32(x1, r1); x1 ^= x0;            \
  x0 += x1; x1 = rotl32(x1, r2); x1 ^= x0;            \
  x0 += x1; x1 = rotl32(x1, r3); x1 ^= x0;            \
  x0 += x1; x1 = rotl32(x1, r4); x1 ^= x0;
  TF_R4(13, 15, 26, 6)   x0 += k1; x1 += k2 + 1u;
  TF_R4(17, 29, 16, 24)  x0 += k2; x1 += k0 + 2u;
  TF_R4(13, 15, 26, 6)   x0 += k0; x1 += k1 + 3u;
  TF_R4(17, 29, 16, 24)  x0 += k1; x1 += k2 + 4u;
  TF_R4(13, 15, 26, 6)   x0 += k2; x1 += k0 + 5u;
#undef TF_R4
  U2 r; r.x = x0; r.y = x1; return r;
}

// VALIDATED (R5): partitionable threefry bits = XOR-fold of both cipher words,
// counter (hi=0, lo=e), key (0, 42).
__device__ __forceinline__ unsigned jax_random_bits(unsigned e) {
  U2 r = threefry2x32(0u, 42u, 0u, e);
  return r.x ^ r.y;
}

__device__ __forceinline__ unsigned mono_key(float zi) {
  unsigned bb = __float_as_uint(zi);
  return bb ^ ((bb >> 31) ? 0xFFFFFFFFu : 0x80000000u);
}

// xT[d][b] = x[b][d]: GEMM stages contiguous [d][b] chunks into LDS.
__global__ __launch_bounds__(256) void transpose_kernel(
    const float* __restrict__ x, float* __restrict__ xT) {
  int i = blockIdx.x * 256 + threadIdx.x;
  if (i < BB * DD) {
    int b = i >> 11;
    int d = i & 2047;
    xT[d * BB + b] = x[i];
  }
}

// Split-K GEMM, LDS-staged x (kills the s_load/SMEM stall seen R5-R8).
// 512 thr: tcol=tid&255, half=tid>>8 (wave-uniform) -> rows half*32..+32.
// 2 cols/thread (col0, col0+256): one x ds_read feeds 2 FMAs, so LDS pipe
// (8 x b128 ~96cyc/dd) stays under VALU (64 FMA ~128cyc/dd).
// x chunk [CH][64] double-buffered, reg-staged (issue-early/write-late).
// (512,2): 256-VGPR budget -- anti scratch-demotion (R5/R8 killer, VGPR=36).
__global__ __launch_bounds__(512, 2) void gemm_splitk_kernel(
    const float* __restrict__ xT, const float* __restrict__ W,
    float* __restrict__ partial, int kc) {
  __shared__ float ldsx[2][CH * BB];          // 2 x 16 KB
  const int tid = threadIdx.x;
  const int tcol = tid & 255;
  const int half = tid >> 8;                  // wave-uniform
  const int b0 = half * 32;
  const int col0 = blockIdx.x * 512 + tcol;
  const int col1 = col0 + 256;
  const int vc0 = (col0 < VV) ? col0 : (VV - 1);
  const int vc1 = (col1 < VV) ? col1 : (VV - 1);
  const int d0 = blockIdx.y * kc;
  const int nch = kc / CH;

  float acc0[32], acc1[32];
#pragma unroll
  for (int j = 0; j < 32; ++j) { acc0[j] = 0.0f; acc1[j] = 0.0f; }

  const float4* gx = (const float4*)(xT + (size_t)d0 * BB);
  // stage chunk 0 (flat float4: chunk = CH*BB floats = 1024 float4)
  {
    float4 ra = gx[tid];
    float4 rb = gx[tid + 512];
    ((float4*)ldsx[0])[tid] = ra;
    ((float4*)ldsx[0])[tid + 512] = rb;
  }
  float4 na, nb;
  if (nch > 1) { na = gx[1024 + tid]; nb = gx[1024 + tid + 512]; }
  __syncthreads();

  const float* wbase = W + (size_t)d0 * VV;
  for (int c = 0; c < nch; ++c) {
    const float* lx = ldsx[c & 1] + b0;
    const float* wp = wbase + (size_t)c * CH * VV;
#pragma unroll 2
    for (int dd = 0; dd < CH; ++dd) {
      const float w0 = wp[(size_t)dd * VV + vc0];
      const float w1 = wp[(size_t)dd * VV + vc1];
      float xv[32];
#pragma unroll
      for (int q = 0; q < 8; ++q)
        *(float4*)&xv[4 * q] = *(const float4*)&lx[dd * BB + 4 * q];
#pragma unroll
      for (int j = 0; j < 32; ++j) {
        acc0[j] = fmaf(xv[j], w0, acc0[j]);
        acc1[j] = fmaf(xv[j], w1, acc1[j]);
      }
    }
    if (c + 1 < nch) {
      __syncthreads();
      ((float4*)ldsx[(c + 1) & 1])[tid] = na;
      ((float4*)ldsx[(c + 1) & 1])[tid + 512] = nb;
      if (c + 2 < nch) {
        na = gx[(size_t)(c + 2) * 1024 + tid];
        nb = gx[(size_t)(c + 2) * 1024 + tid + 512];
      }
      __syncthreads();
    }
  }

  float* pbase = partial + ((size_t)blockIdx.y * BB + b0) * VV;
  if (col0 < VV) {
#pragma unroll
    for (int j = 0; j < 32; ++j) pbase[(size_t)j * VV + col0] = acc0[j];
  }
  if (col1 < VV) {
#pragma unroll
    for (int j = 0; j < 32; ++j) pbase[(size_t)j * VV + col1] = acc1[j];
  }
}

// float4 flat reduce: partial planes are [s][flat], flat-contiguous.
__global__ __launch_bounds__(256) void reduce_bias_kernel(
    const float* __restrict__ partial, const float* __restrict__ bias,
    float* __restrict__ logits, int sk) {
  const size_t tot4 = (size_t)BB * VV / 4;   // 3216448 / 4 = 804112
  size_t i = (size_t)blockIdx.x * 256 + threadIdx.x;
  if (i >= tot4) return;
  float4 acc;
  {
    size_t f = i * 4;
    int v0 = (int)(f % VV);
    acc.x = bias[v0];
    acc.y = bias[(v0 + 1 == VV) ? 0 : v0 + 1];
    acc.z = bias[(v0 + 1 >= VV) ? (v0 + 2 - VV) : v0 + 2];
    acc.w = bias[(v0 + 2 >= VV) ? (v0 + 3 - VV) : v0 + 3];
  }
  for (int s = 0; s < sk; ++s) {
    float4 p = ((const float4*)(partial + (size_t)s * BB * VV))[i];
    acc.x += p.x; acc.y += p.y; acc.z += p.z; acc.w += p.w;
  }
  ((float4*)logits)[i] = acc;
}

// Legacy fused GEMM (validated R5) — fallback if ws too small for split-K.
__global__ __launch_bounds__(256, 1) void gemm_kernel(
    const float* __restrict__ xT, const float* __restrict__ W,
    const float* __restrict__ bias, float* __restrict__ logits) {
  const int v = blockIdx.x * 256 + threadIdx.x;
  const int vc = (v < VV) ? v : (VV - 1);
  float acc[BB];
#pragma unroll
  for (int b = 0; b < BB; ++b) acc[b] = 0.0f;
  const float* wp = W + vc;
#pragma unroll 2
  for (int d = 0; d < DD; ++d) {
    const float w = wp[(size_t)d * VV];
    const float* xr = xT + d * BB;
#pragma unroll
    for (int b = 0; b < BB; ++b) acc[b] = fmaf(xr[b], w, acc[b]);
  }
  if (v < VV) {
    const float bv = bias[v];
#pragma unroll
    for (int b = 0; b < BB; ++b) logits[(size_t)b * VV + v] = acc[b] + bv;
  }
}

// Per row: max -> histogram of w=expf(z-m) binned by (m-z)*256 -> scan to find
// boundary bin (S_above <= C < S_above+bin) -> exact prefix sums within bin
// ((key desc, idx asc) order, same semantics as R5's validated binary search)
// -> t* = min kept key -> gumbel argmax over key >= t*. 4 logits passes vs 35.
__global__ __launch_bounds__(1024) void nucleus_sample_kernel(
    const float* __restrict__ logits, int* __restrict__ out) {
  __shared__ double sd[1024];
  __shared__ float sf[1024];
  __shared__ unsigned su[1024];
  __shared__ int si[1024];
  __shared__ double bins[NB];
  __shared__ int cidx[MAXC];
  __shared__ unsigned ckey[MAXC];
  __shared__ double cw[MAXC];
  __shared__ int ccount;
  __shared__ int sh_chunk;
  __shared__ int sh_bstar;
  __shared__ double sh_sabove;

  const int row = blockIdx.x;
  const int tid = threadIdx.x;
  const float* z = logits + (size_t)row * VV;

  for (int i = tid; i < NB; i += 1024) bins[i] = 0.0;
  if (tid == 0) { ccount = 0; sh_chunk = -1; sh_bstar = -1; }
  __syncthreads();

  // pass 1: row max
  float mx = -3.4e38f;
  for (int i = tid; i < VV; i += 1024) mx = fmaxf(mx, z[i]);
  sf[tid] = mx; __syncthreads();
  for (int s = 512; s > 0; s >>= 1) {
    if (tid < s) sf[tid] = fmaxf(sf[tid], sf[tid + s]);
    __syncthreads();
  }
  const float m = sf[0];
  __syncthreads();

  // pass 2: histogram
  for (int i = tid; i < VV; i += 1024) {
    float zi = z[i];
    int bin = (int)((m - zi) * 256.0f);
    bin = (bin < 0) ? 0 : ((bin > NB - 1) ? NB - 1 : bin);
    atomicAdd(&bins[bin], (double)expf(zi - m));
  }
  __syncthreads();

  // inclusive scan over 1024 chunk-sums (4 bins/chunk), f64
  {
    double c = bins[4 * tid] + bins[4 * tid + 1] + bins[4 * tid + 2] + bins[4 * tid + 3];
    sd[tid] = c; __syncthreads();
    for (int off = 1; off < 1024; off <<= 1) {
      double vv = (tid >= off) ? sd[tid - off] : 0.0;
      __syncthreads();
      sd[tid] += vv;
      __syncthreads();
    }
  }
  const double Z = sd[1023];
  const double C = (double)0.9f * Z;

  if (sd[tid] > C && (tid == 0 || sd[tid - 1] <= C)) sh_chunk = tid;
  __syncthreads();
  if (tid == 0) {
    int tc = sh_chunk;
    if (tc >= 0) {
      double run = (tc > 0) ? sd[tc - 1] : 0.0;
      for (int k = 0; k < 4; ++k) {
        double bw = bins[4 * tc + k];
        if (run + bw > C) { sh_bstar = 4 * tc + k; sh_sabove = run; break; }
        run += bw;
      }
    }
  }
  __syncthreads();
  const int bstar = sh_bstar;
  unsigned tkey = 0u;

  if (bstar >= 0) {
    const double Sab = sh_sabove;
    // pass 3: collect boundary-bin elements
    for (int i = tid; i < VV; i += 1024) {
      float zi = z[i];
      int bin = (int)((m - zi) * 256.0f);
      bin = (bin < 0) ? 0 : ((bin > NB - 1) ? NB - 1 : bin);
      if (bin == bstar) {
        int slot = atomicAdd(&ccount, 1);
        if (slot < MAXC) {
          ckey[slot] = mono_key(zi);
          cidx[slot] = i;
          cw[slot] = (double)expf(zi - m);
        }
      }
    }
    __syncthreads();
    int n = ccount; if (n > MAXC) n = MAXC;
    // kept iff exclusive prefix (in (key desc, idx asc) order) <= C
    unsigned mk = 0xFFFFFFFFu;
    for (int i = tid; i < n; i += 1024) {
      unsigned ki = ckey[i]; int ii = cidx[i];
      double T = Sab;
      for (int j = 0; j < n; ++j) {
        unsigned kj = ckey[j];
        if (kj > ki || (kj == ki && cidx[j] < ii)) T += cw[j];
      }
      if (T <= C) mk = (ki < mk) ? ki : mk;
    }
    su[tid] = mk; __syncthreads();
    for (int s = 512; s > 0; s >>= 1) {
      if (tid < s) su[tid] = min(su[tid], su[tid + s]);
      __syncthreads();
    }
    tkey = su[0];
    __syncthreads();
  }
  const unsigned tstar = tkey;

  // pass 4: gumbel argmax over kept tokens (validated R5 code path)
  float best = -3.4e38f; int bidx = 0x7FFFFFFF;
  for (int i = tid; i < VV; i += 1024) {
    float zi = z[i];
    if (mono_key(zi) < tstar) continue;
    unsigned e = (unsigned)row * (unsigned)VV + (unsigned)i;
    unsigned bits = jax_random_bits(e);
    float f = __uint_as_float((bits >> 9) | 0x3F800000u) - 1.0f;
    float u = fmaxf(1.17549435082228750797e-38f, f);
    float g = -logf(-logf(u));
    float sc = zi + g;
    if (sc > best) { best = sc; bidx = i; }
  }
  sf[tid] = best; si[tid] = bidx; __syncthreads();
  for (int s = 512; s > 0; s >>= 1) {
    if (tid < s) {
      float ob = sf[tid + s]; int oi = si[tid + s];
      if (ob > sf[tid] || (ob == sf[tid] && oi < si[tid])) {
        sf[tid] = ob; si[tid] = oi;
      }
    }
    __syncthreads();
  }
  if (tid == 0) out[row] = si[0];
}

extern "C" void kernel_launch(void* const* d_in, const int* in_sizes, int n_in,
                              void* d_out, int out_size, void* d_ws, size_t ws_size,
                              hipStream_t stream) {
  const float* x = (const float*)d_in[0];
  const float* W = (const float*)d_in[1];
  const float* bias = (const float*)d_in[2];
  int* out = (int*)d_out;
  char* ws = (char*)d_ws;

  const size_t offXT = 0;                       // 524288 B
  const size_t offLog = 524288;                 // 12865792 B
  const size_t offPart = offLog + 12865792;     // sk * 12865792 B
  float* xT = (float*)(ws + offXT);
  float* logits = (float*)(ws + offLog);
  float* partial = (float*)(ws + offPart);

  int sk = 0;
  for (int c = 8; c >= 2; c >>= 1) {
    if (offPart + (size_t)c * 12865792 <= ws_size) { sk = c; break; }
  }

  transpose_kernel<<<(BB * DD + 255) / 256, 256, 0, stream>>>(x, xT);
  if (sk) {
    dim3 g((VV + 511) / 512, sk);
    gemm_splitk_kernel<<<g, 512, 0, stream>>>(xT, W, partial, DD / sk);
    const size_t tot4 = (size_t)BB * VV / 4;
    reduce_bias_kernel<<<(unsigned)((tot4 + 255) / 256), 256, 0, stream>>>(
        partial, bias, logits, sk);
  } else {
    gemm_kernel<<<(VV + 255) / 256, 256, 0, stream>>>(xT, W, bias, logits);
  }
  nucleus_sample_kernel<<<BB, 1024, 0, stream>>>(logits, out);
}

// Round 10
// 340.406 us; speedup vs baseline: 4.0764x; 1.2589x over previous
//
#include <hip/hip_runtime.h>
#include <hip/hip_bf16.h>
#include <stdint.h>

#define BB 64
#define DD 2048
#define VV 50257
#define NB 4096      // histogram bins
#define MAXC 2048    // boundary-bin collect capacity

struct U2 { unsigned x, y; };

__device__ __forceinline__ unsigned rotl32(unsigned v, int r) {
  return (v << r) | (v >> (32 - r));
}

// JAX threefry2x32 (jax/_src/prng.py lowering), 20 rounds.
__device__ __forceinline__ U2 threefry2x32(unsigned k0, unsigned k1,
                                           unsigned x0, unsigned x1) {
  unsigned k2 = k0 ^ k1 ^ 0x1BD11BDAu;
  x0 += k0; x1 += k1;
#define TF_R4(r1, r2, r3, r4)                         \
  x0 += x1; x1 = rotl32(x1, r1); x1 ^= x0;            \
  x0 += x1; x1 = rotl32(x1, r2); x1 ^= x0;            \
  x0 += x1; x1 = rotl32(x1, r3); x1 ^= x0;            \
  x0 += x1; x1 = rotl32(x1, r4); x1 ^= x0;
  TF_R4(13, 15, 26, 6)   x0 += k1; x1 += k2 + 1u;
  TF_R4(17, 29, 16, 24)  x0 += k2; x1 += k0 + 2u;
  TF_R4(13, 15, 26, 6)   x0 += k0; x1 += k1 + 3u;
  TF_R4(17, 29, 16, 24)  x0 += k1; x1 += k2 + 4u;
  TF_R4(13, 15, 26, 6)   x0 += k2; x1 += k0 + 5u;
#undef TF_R4
  U2 r; r.x = x0; r.y = x1; return r;
}

// VALIDATED (R5): partitionable threefry bits = XOR-fold of both cipher words,
// counter (hi=0, lo=e), key (0, 42).
__device__ __forceinline__ unsigned jax_random_bits(unsigned e) {
  U2 r = threefry2x32(0u, 42u, 0u, e);
  return r.x ^ r.y;
}

__device__ __forceinline__ unsigned mono_key(float zi) {
  unsigned bb = __float_as_uint(zi);
  return bb ^ ((bb >> 31) ? 0xFFFFFFFFu : 0x80000000u);
}

// xT[d][b] = x[b][d] so GEMM inner loop reads wave-uniform x (SGPR s_load path
// — leaves the VGPR file to acc[64]; this is why R6's shape is the fast one).
__global__ __launch_bounds__(256) void transpose_kernel(
    const float* __restrict__ x, float* __restrict__ xT) {
  int i = blockIdx.x * 256 + threadIdx.x;
  if (i < BB * DD) {
    int b = i >> 11;
    int d = i & 2047;
    xT[d * BB + b] = x[i];
  }
}

// Split-K GEMM — BYTE-EXACT R6 structure (best measured; every restructure
// R7/R8/R9 triggered accumulator demotion to AGPR/scratch and regressed).
// Only the launch changes this round: sk=16 (kc=128) for 2x resident waves.
__global__ __launch_bounds__(256, 1) void gemm_splitk_kernel(
    const float* __restrict__ xT, const float* __restrict__ W,
    float* __restrict__ partial, int kc) {
  const int v = blockIdx.x * 256 + threadIdx.x;
  const int vc = (v < VV) ? v : (VV - 1);
  const int d0 = blockIdx.y * kc;
  float acc[BB];
#pragma unroll
  for (int b = 0; b < BB; ++b) acc[b] = 0.0f;
  const float* wp = W + (size_t)d0 * VV + vc;
  const float* xr = xT + d0 * BB;
#pragma unroll 2
  for (int d = 0; d < kc; ++d) {
    const float w = wp[(size_t)d * VV];
    const float* xv = xr + d * BB;   // wave-uniform -> scalar loads
#pragma unroll
    for (int b = 0; b < BB; ++b) acc[b] = fmaf(xv[b], w, acc[b]);
  }
  if (v < VV) {
    float* pp = partial + (size_t)blockIdx.y * BB * VV + v;
#pragma unroll
    for (int b = 0; b < BB; ++b) pp[(size_t)b * VV] = acc[b];
  }
}

// float4 flat reduce: partial planes are [s][flat], flat-contiguous.
__global__ __launch_bounds__(256) void reduce_bias_kernel(
    const float* __restrict__ partial, const float* __restrict__ bias,
    float* __restrict__ logits, int sk) {
  const size_t tot4 = (size_t)BB * VV / 4;   // 3216448 / 4 = 804112
  size_t i = (size_t)blockIdx.x * 256 + threadIdx.x;
  if (i >= tot4) return;
  float4 acc;
  {
    size_t f = i * 4;
    int v0 = (int)(f % VV);
    acc.x = bias[v0];
    acc.y = bias[(v0 + 1 == VV) ? 0 : v0 + 1];
    acc.z = bias[(v0 + 1 >= VV) ? (v0 + 2 - VV) : v0 + 2];
    acc.w = bias[(v0 + 2 >= VV) ? (v0 + 3 - VV) : v0 + 3];
  }
  for (int s = 0; s < sk; ++s) {
    float4 p = ((const float4*)(partial + (size_t)s * BB * VV))[i];
    acc.x += p.x; acc.y += p.y; acc.z += p.z; acc.w += p.w;
  }
  ((float4*)logits)[i] = acc;
}

// Legacy fused GEMM (validated R5) — fallback if ws too small for split-K.
__global__ __launch_bounds__(256, 1) void gemm_kernel(
    const float* __restrict__ xT, const float* __restrict__ W,
    const float* __restrict__ bias, float* __restrict__ logits) {
  const int v = blockIdx.x * 256 + threadIdx.x;
  const int vc = (v < VV) ? v : (VV - 1);
  float acc[BB];
#pragma unroll
  for (int b = 0; b < BB; ++b) acc[b] = 0.0f;
  const float* wp = W + vc;
#pragma unroll 2
  for (int d = 0; d < DD; ++d) {
    const float w = wp[(size_t)d * VV];
    const float* xr = xT + d * BB;
#pragma unroll
    for (int b = 0; b < BB; ++b) acc[b] = fmaf(xr[b], w, acc[b]);
  }
  if (v < VV) {
    const float bv = bias[v];
#pragma unroll
    for (int b = 0; b < BB; ++b) logits[(size_t)b * VV + v] = acc[b] + bv;
  }
}

// Per row: max -> histogram of w=expf(z-m) binned by (m-z)*256 -> scan to find
// boundary bin (S_above <= C < S_above+bin) -> exact prefix sums within bin
// ((key desc, idx asc) order, same semantics as R5's validated binary search)
// -> t* = min kept key -> gumbel argmax over key >= t*. 4 logits passes vs 35.
__global__ __launch_bounds__(1024) void nucleus_sample_kernel(
    const float* __restrict__ logits, int* __restrict__ out) {
  __shared__ double sd[1024];
  __shared__ float sf[1024];
  __shared__ unsigned su[1024];
  __shared__ int si[1024];
  __shared__ double bins[NB];
  __shared__ int cidx[MAXC];
  __shared__ unsigned ckey[MAXC];
  __shared__ double cw[MAXC];
  __shared__ int ccount;
  __shared__ int sh_chunk;
  __shared__ int sh_bstar;
  __shared__ double sh_sabove;

  const int row = blockIdx.x;
  const int tid = threadIdx.x;
  const float* z = logits + (size_t)row * VV;

  for (int i = tid; i < NB; i += 1024) bins[i] = 0.0;
  if (tid == 0) { ccount = 0; sh_chunk = -1; sh_bstar = -1; }
  __syncthreads();

  // pass 1: row max
  float mx = -3.4e38f;
  for (int i = tid; i < VV; i += 1024) mx = fmaxf(mx, z[i]);
  sf[tid] = mx; __syncthreads();
  for (int s = 512; s > 0; s >>= 1) {
    if (tid < s) sf[tid] = fmaxf(sf[tid], sf[tid + s]);
    __syncthreads();
  }
  const float m = sf[0];
  __syncthreads();

  // pass 2: histogram
  for (int i = tid; i < VV; i += 1024) {
    float zi = z[i];
    int bin = (int)((m - zi) * 256.0f);
    bin = (bin < 0) ? 0 : ((bin > NB - 1) ? NB - 1 : bin);
    atomicAdd(&bins[bin], (double)expf(zi - m));
  }
  __syncthreads();

  // inclusive scan over 1024 chunk-sums (4 bins/chunk), f64
  {
    double c = bins[4 * tid] + bins[4 * tid + 1] + bins[4 * tid + 2] + bins[4 * tid + 3];
    sd[tid] = c; __syncthreads();
    for (int off = 1; off < 1024; off <<= 1) {
      double vv = (tid >= off) ? sd[tid - off] : 0.0;
      __syncthreads();
      sd[tid] += vv;
      __syncthreads();
    }
  }
  const double Z = sd[1023];
  const double C = (double)0.9f * Z;

  if (sd[tid] > C && (tid == 0 || sd[tid - 1] <= C)) sh_chunk = tid;
  __syncthreads();
  if (tid == 0) {
    int tc = sh_chunk;
    if (tc >= 0) {
      double run = (tc > 0) ? sd[tc - 1] : 0.0;
      for (int k = 0; k < 4; ++k) {
        double bw = bins[4 * tc + k];
        if (run + bw > C) { sh_bstar = 4 * tc + k; sh_sabove = run; break; }
        run += bw;
      }
    }
  }
  __syncthreads();
  const int bstar = sh_bstar;
  unsigned tkey = 0u;

  if (bstar >= 0) {
    const double Sab = sh_sabove;
    // pass 3: collect boundary-bin elements
    for (int i = tid; i < VV; i += 1024) {
      float zi = z[i];
      int bin = (int)((m - zi) * 256.0f);
      bin = (bin < 0) ? 0 : ((bin > NB - 1) ? NB - 1 : bin);
      if (bin == bstar) {
        int slot = atomicAdd(&ccount, 1);
        if (slot < MAXC) {
          ckey[slot] = mono_key(zi);
          cidx[slot] = i;
          cw[slot] = (double)expf(zi - m);
        }
      }
    }
    __syncthreads();
    int n = ccount; if (n > MAXC) n = MAXC;
    // kept iff exclusive prefix (in (key desc, idx asc) order) <= C
    unsigned mk = 0xFFFFFFFFu;
    for (int i = tid; i < n; i += 1024) {
      unsigned ki = ckey[i]; int ii = cidx[i];
      double T = Sab;
      for (int j = 0; j < n; ++j) {
        unsigned kj = ckey[j];
        if (kj > ki || (kj == ki && cidx[j] < ii)) T += cw[j];
      }
      if (T <= C) mk = (ki < mk) ? ki : mk;
    }
    su[tid] = mk; __syncthreads();
    for (int s = 512; s > 0; s >>= 1) {
      if (tid < s) su[tid] = min(su[tid], su[tid + s]);
      __syncthreads();
    }
    tkey = su[0];
    __syncthreads();
  }
  const unsigned tstar = tkey;

  // pass 4: gumbel argmax over kept tokens (validated R5 code path)
  float best = -3.4e38f; int bidx = 0x7FFFFFFF;
  for (int i = tid; i < VV; i += 1024) {
    float zi = z[i];
    if (mono_key(zi) < tstar) continue;
    unsigned e = (unsigned)row * (unsigned)VV + (unsigned)i;
    unsigned bits = jax_random_bits(e);
    float f = __uint_as_float((bits >> 9) | 0x3F800000u) - 1.0f;
    float u = fmaxf(1.17549435082228750797e-38f, f);
    float g = -logf(-logf(u));
    float sc = zi + g;
    if (sc > best) { best = sc; bidx = i; }
  }
  sf[tid] = best; si[tid] = bidx; __syncthreads();
  for (int s = 512; s > 0; s >>= 1) {
    if (tid < s) {
      float ob = sf[tid + s]; int oi = si[tid + s];
      if (ob > sf[tid] || (ob == sf[tid] && oi < si[tid])) {
        sf[tid] = ob; si[tid] = oi;
      }
    }
    __syncthreads();
  }
  if (tid == 0) out[row] = si[0];
}

extern "C" void kernel_launch(void* const* d_in, const int* in_sizes, int n_in,
                              void* d_out, int out_size, void* d_ws, size_t ws_size,
                              hipStream_t stream) {
  const float* x = (const float*)d_in[0];
  const float* W = (const float*)d_in[1];
  const float* bias = (const float*)d_in[2];
  int* out = (int*)d_out;
  char* ws = (char*)d_ws;

  const size_t offXT = 0;                       // 524288 B
  const size_t offLog = 524288;                 // 12865792 B
  const size_t offPart = offLog + 12865792;     // sk * 12865792 B
  float* xT = (float*)(ws + offXT);
  float* logits = (float*)(ws + offLog);
  float* partial = (float*)(ws + offPart);

  int sk = 0;
  for (int c = 16; c >= 2; c >>= 1) {
    if (offPart + (size_t)c * 12865792 <= ws_size) { sk = c; break; }
  }

  transpose_kernel<<<(BB * DD + 255) / 256, 256, 0, stream>>>(x, xT);
  const int vblocks = (VV + 255) / 256;
  if (sk) {
    dim3 g(vblocks, sk);
    gemm_splitk_kernel<<<g, 256, 0, stream>>>(xT, W, partial, DD / sk);
    const size_t tot4 = (size_t)BB * VV / 4;
    reduce_bias_kernel<<<(unsigned)((tot4 + 255) / 256), 256, 0, stream>>>(
        partial, bias, logits, sk);
  } else {
    gemm_kernel<<<vblocks, 256, 0, stream>>>(xT, W, bias, logits);
  }
  nucleus_sample_kernel<<<BB, 1024, 0, stream>>>(logits, out);
}